// Round 1
// baseline (177.989 us; speedup 1.0000x reference)
//
#include <hip/hip_runtime.h>

// out[i][j] = (Z[i] == Z[j]) ? 1.0f : 0.0f, N = 16384, out float32.
// Write-BW-bound: 1 GiB of stores. Each thread stores one float4 per row,
// looping ROWS_PER_BLOCK rows to amortize the column-label load.

constexpr int N = 16384;
constexpr int ROWS_PER_BLOCK = 16;
constexpr int THREADS = 256;           // covers 256*4 = 1024 columns per block

__global__ __launch_bounds__(THREADS) void category_equal_kernel(
    const int* __restrict__ Z, float* __restrict__ out) {
    const int col = (blockIdx.x * THREADS + threadIdx.x) * 4;   // first of 4 cols
    const int row0 = blockIdx.y * ROWS_PER_BLOCK;

    // Column labels for this thread's 4 outputs: one vectorized 16B load.
    const int4 zc = *reinterpret_cast<const int4*>(&Z[col]);

    float4* out4 = reinterpret_cast<float4*>(out);
    const int col4 = col >> 2;

    #pragma unroll
    for (int r = 0; r < ROWS_PER_BLOCK; ++r) {
        const int row = row0 + r;
        const int zr = Z[row];          // broadcast, L1-hit
        float4 v;
        v.x = (zc.x == zr) ? 1.0f : 0.0f;
        v.y = (zc.y == zr) ? 1.0f : 0.0f;
        v.z = (zc.z == zr) ? 1.0f : 0.0f;
        v.w = (zc.w == zr) ? 1.0f : 0.0f;
        out4[(size_t)row * (N / 4) + col4] = v;
    }
}

extern "C" void kernel_launch(void* const* d_in, const int* in_sizes, int n_in,
                              void* d_out, int out_size, void* d_ws, size_t ws_size,
                              hipStream_t stream) {
    const int* Z = (const int*)d_in[0];
    float* out = (float*)d_out;

    dim3 block(THREADS);
    dim3 grid(N / (THREADS * 4), N / ROWS_PER_BLOCK);   // (16, 1024)
    category_equal_kernel<<<grid, block, 0, stream>>>(Z, out);
}